// Round 7
// baseline (2189.047 us; speedup 1.0000x reference)
//
#include <hip/hip_runtime.h>
#include <hip/hip_bf16.h>
#include <cstdint>

// ---------------------------------------------------------------------------
// MolGraphEncoder r7: fused layer with wave-private fp32 LDS accumulator.
// Each wave owns 16 contiguous rows: init (self) -> flat 3-stage-pipelined
// edge stream (csr idx -> row load -> LDS f32 add) -> MFMA readback.
// No __syncthreads in the layer kernel. Activations in pair layout
// (u32 slot i = bf16 cols (i, i+K/2)) so LDS adds are bank-conflict-free.
// ---------------------------------------------------------------------------

typedef __attribute__((ext_vector_type(8))) short short8;
typedef __attribute__((ext_vector_type(4))) float f32x4;

__device__ __forceinline__ float b2f(unsigned int hi16) {
    return __builtin_bit_cast(float, hi16);
}
__device__ __forceinline__ unsigned short f2b(float f) {  // RTN-even
    unsigned int u = __builtin_bit_cast(unsigned int, f);
    u += 0x7fffu + ((u >> 16) & 1u);
    return (unsigned short)(u >> 16);
}
__device__ __forceinline__ unsigned int packbf(float lo, float hi) {
    return ((unsigned int)f2b(hi) << 16) | f2b(lo);
}
// swizzled word address within the 64x128-word LDS tile
__device__ __forceinline__ int physw(int r, int wd) {
    return (r << 7) + ((((wd >> 3) ^ (r & 15)) << 3) | (wd & 7));
}

__global__ void k_count(const int* __restrict__ dst, int* __restrict__ cnt, int E) {
    int e = blockIdx.x * blockDim.x + threadIdx.x;
    if (e < E) atomicAdd(&cnt[dst[e]], 1);
}

// --- scan (2048/block) + fused dis = rsqrt(deg+1) ---------------------------
__global__ void k_scan1(const int* __restrict__ in, int* __restrict__ out1,
                        int* __restrict__ bsum, float* __restrict__ dis, int n) {
    __shared__ int s[256];
    int t = threadIdx.x;
    int base = blockIdx.x * 2048 + t * 8;
    int v[8];
    int run = 0;
#pragma unroll
    for (int i = 0; i < 8; ++i) {
        int idx = base + i;
        int x = (idx < n) ? in[idx] : 0;
        if (idx < n) dis[idx] = rsqrtf((float)x + 1.0f);
        run += x;
        v[i] = run;
    }
    s[t] = run;
    __syncthreads();
    for (int off = 1; off < 256; off <<= 1) {
        int add = (t >= off) ? s[t - off] : 0;
        __syncthreads();
        s[t] += add;
        __syncthreads();
    }
    int pre = (t > 0) ? s[t - 1] : 0;
#pragma unroll
    for (int i = 0; i < 8; ++i) {
        int idx = base + i;
        if (idx < n) out1[idx] = v[i] + pre;
    }
    if (t == 255) bsum[blockIdx.x] = s[255];
}

__global__ void k_scan2(int* bsum, int nb) {
    __shared__ int s[256];
    int t = threadIdx.x;
    s[t] = (t < nb) ? bsum[t] : 0;
    __syncthreads();
    for (int off = 1; off < 256; off <<= 1) {
        int add = (t >= off) ? s[t - off] : 0;
        __syncthreads();
        s[t] += add;
        __syncthreads();
    }
    if (t < nb) bsum[t] = s[t];
}

__global__ void k_scan3(int* __restrict__ rowstart, const int* __restrict__ bsum, int n) {
    int b = blockIdx.x, t = threadIdx.x;
    if (b == 0) {
        if (t == 0) rowstart[0] = 0;
        return;
    }
    int add = bsum[b - 1];
    int* out1 = rowstart + 1;
    int base = b * 2048 + t * 8;
#pragma unroll
    for (int i = 0; i < 8; ++i) {
        int idx = base + i;
        if (idx < n) out1[idx] += add;
    }
}

// fill CSR (src + dst), position = rowstart[d] + zero-based atomic offset
__global__ void k_fill(const int* __restrict__ src, const int* __restrict__ dst,
                       const int* __restrict__ rowstart, int* __restrict__ cur0,
                       int* __restrict__ csr_src, int* __restrict__ csr_dst, int E) {
    int e = blockIdx.x * blockDim.x + threadIdx.x;
    if (e >= E) return;
    int d = dst[e];
    int pos = rowstart[d] + atomicAdd(&cur0[d], 1);
    csr_src[pos] = src[e];
    csr_dst[pos] = d;
}

// --- pack all 3 weights into MFMA B-fragment layout (bf16, K padded) --------
__global__ void k_cvtw3(const float* __restrict__ W0, const float* __restrict__ W1,
                        const float* __restrict__ W2, unsigned short* __restrict__ wp0,
                        unsigned short* __restrict__ wp1, unsigned short* __restrict__ wp2) {
    int tid = blockIdx.x * blockDim.x + threadIdx.x;
    const float* W;
    unsigned short* o;
    int Ksrc, f;
    if (tid < 3 * 512) { W = W0; o = wp0; Ksrc = 82; f = tid; }
    else if (tid < 7 * 512) { W = W1; o = wp1; Ksrc = 128; f = tid - 3 * 512; }
    else if (tid < 11 * 512) { W = W2; o = wp2; Ksrc = 128; f = tid - 7 * 512; }
    else return;
    int lane = f & 63, fr = f >> 6;
    int m = fr >> 3, ct = fr & 7;
    int col = ct * 16 + (lane & 15);
    int kb = m * 32 + ((lane >> 4) << 3);
    unsigned short v[8];
#pragma unroll
    for (int j = 0; j < 8; ++j) {
        int k = kb + j;
        v[j] = (k < Ksrc) ? f2b(W[k * 128 + col]) : (unsigned short)0;
    }
    *(short8*)(o + (size_t)f * 8) = *(short8*)v;
}

// --- xd: pair layout, slot i of row v = bf16(dis*x[i], dis*x[i+48]) ---------
__global__ __launch_bounds__(256) void k_xd(const float* __restrict__ x,
                                            const float* __restrict__ dis,
                                            unsigned int* __restrict__ xd, int n) {
    int tid = blockIdx.x * blockDim.x + threadIdx.x;
    if (tid >= n * 48) return;
    int v = tid / 48;
    int i = tid - v * 48;
    float dv = dis[v];
    const float* xv = x + (size_t)v * 82;
    float lo = dv * xv[i];  // i < 48 < 82
    float hi = (i + 48 < 82) ? dv * xv[i + 48] : 0.f;
    xd[tid] = packbf(lo, hi);
}

// --- fused GCN layer, wave-private rows, pipelined gather -------------------
// input rows: RU u32 pair-layout (slot i = cols (i, i+RU)), dis-prescaled.
// agg[v] = dis[v]*(in[v] + sum in[u]); out = relu(agg @ W + b) [pair layout]
template <int KS, bool SCALE, bool GATE>
__global__ __launch_bounds__(256, 5) void k_fused(
    const unsigned int* __restrict__ hd, const float* __restrict__ dis,
    const int* __restrict__ rowstart, const int* __restrict__ csr_src,
    const int* __restrict__ csr_dst, const unsigned short* __restrict__ Wp,
    const float* __restrict__ bias, unsigned int* __restrict__ out,
    const float* __restrict__ gw, const float* __restrict__ gb,
    float* __restrict__ gate, int n) {
    constexpr int RU = KS * 16;  // u32 per input row (48 or 96->K/2)
    __shared__ float T[64 * 128];  // 32 KB, swizzled, wave-private 16-row strips
    int t = threadIdx.x, lane = t & 63, w = t >> 6;
    int tile = blockIdx.x * 64;
    const bool act = (RU == 64) ? true : (lane < RU);
    const int li = act ? lane : 0;
    int v0w = tile + (w << 4);

    // ---- init: self terms into own strip (plain writes) ----
#pragma unroll 4
    for (int i = 0; i < 16; ++i) {
        int r = (w << 4) + i;
        int v = tile + r;
        float flo = 0.f, fhi = 0.f;
        if (v < n && act) {
            unsigned int s = hd[(size_t)v * RU + li];
            flo = b2f(s << 16);
            fhi = b2f(s & 0xffff0000u);
        }
        if (act) {
            T[physw(r, li)] = flo;
            T[physw(r, li + RU)] = fhi;
        }
    }

    // ---- edge stream: 3-stage pipeline (idx -> rows -> LDS add) ----
    {
        int a = v0w < n ? v0w : n;
        int b = v0w + 16 < n ? v0w + 16 : n;
        if (b < a) b = a;
        int el = rowstart[a], eh = rowstart[b];

#define LDIDX(E, S0, S1, S2, S3, D0, D1, D2, D3)                        \
        do {                                                            \
            int _rm = eh - (E);                                         \
            S0 = (_rm > 0) ? csr_src[(E)] : 0;                          \
            D0 = (_rm > 0) ? csr_dst[(E)] : tile;                       \
            S1 = (_rm > 1) ? csr_src[(E) + 1] : 0;                      \
            D1 = (_rm > 1) ? csr_dst[(E) + 1] : tile;                   \
            S2 = (_rm > 2) ? csr_src[(E) + 2] : 0;                      \
            D2 = (_rm > 2) ? csr_dst[(E) + 2] : tile;                   \
            S3 = (_rm > 3) ? csr_src[(E) + 3] : 0;                      \
            D3 = (_rm > 3) ? csr_dst[(E) + 3] : tile;                   \
        } while (0)

#define CONS1(R, D)                                                     \
        do {                                                            \
            int _rr = (D) - tile;                                       \
            atomicAdd(&T[physw(_rr, li)], b2f((R) << 16));              \
            atomicAdd(&T[physw(_rr, li + RU)], b2f((R) & 0xffff0000u)); \
        } while (0)

        if (el < eh) {
            int s0B, s1B, s2B, s3B, d0A, d1A, d2A, d3A, d0B, d1B, d2B, d3B;
            unsigned int r0A, r1A, r2A, r3A;
            {
                int s0A, s1A, s2A, s3A;
                LDIDX(el, s0A, s1A, s2A, s3A, d0A, d1A, d2A, d3A);
                LDIDX(el + 4, s0B, s1B, s2B, s3B, d0B, d1B, d2B, d3B);
                r0A = hd[(size_t)s0A * RU + li];
                r1A = hd[(size_t)s1A * RU + li];
                r2A = hd[(size_t)s2A * RU + li];
                r3A = hd[(size_t)s3A * RU + li];
            }
            for (int e = el; e < eh; e += 4) {
                int s0C, s1C, s2C, s3C, d0C, d1C, d2C, d3C;
                LDIDX(e + 8, s0C, s1C, s2C, s3C, d0C, d1C, d2C, d3C);
                unsigned int r0B = hd[(size_t)s0B * RU + li];
                unsigned int r1B = hd[(size_t)s1B * RU + li];
                unsigned int r2B = hd[(size_t)s2B * RU + li];
                unsigned int r3B = hd[(size_t)s3B * RU + li];
                int rm = eh - e;
                if (act) {
                    if (rm > 0) CONS1(r0A, d0A);
                    if (rm > 1) CONS1(r1A, d1A);
                    if (rm > 2) CONS1(r2A, d2A);
                    if (rm > 3) CONS1(r3A, d3A);
                }
                r0A = r0B; r1A = r1B; r2A = r2B; r3A = r3B;
                d0A = d0B; d1A = d1B; d2A = d2B; d3A = d3B;
                s0B = s0C; s1B = s1C; s2B = s2C; s3B = s3C;
                d0B = d0C; d1B = d1C; d2B = d2C; d3B = d3C;
            }
        }
#undef LDIDX
#undef CONS1
    }

    // ---- MFMA readback (own strip only; no barrier needed) ----
    int r0 = lane & 15, ch = lane >> 4;
    int myr = (w << 4) + r0;
    int vrow = tile + myr;
    float dva = (vrow < n) ? dis[vrow] : 0.f;
    f32x4 acc[8];
#pragma unroll
    for (int ct = 0; ct < 8; ++ct) acc[ct] = (f32x4){0.f, 0.f, 0.f, 0.f};
#pragma unroll
    for (int m = 0; m < KS; ++m) {
        int pa = physw(myr, m * 32 + ch * 8);
        float4 f0 = *(float4*)&T[pa];
        float4 f1 = *(float4*)&T[pa + 4];
        unsigned int aw[4] = {packbf(dva * f0.x, dva * f0.y), packbf(dva * f0.z, dva * f0.w),
                              packbf(dva * f1.x, dva * f1.y), packbf(dva * f1.z, dva * f1.w)};
        short8 afrag = *(short8*)aw;
        const short8* wf = (const short8*)Wp + ((size_t)(m * 8) * 64 + lane);
#pragma unroll
        for (int ct = 0; ct < 8; ++ct) {
            short8 bfrag = wf[ct * 64];
            acc[ct] = __builtin_amdgcn_mfma_f32_16x16x32_bf16(afrag, bfrag, acc[ct], 0, 0, 0);
        }
    }

    // ---- epilogue (pair-layout out) ----
    float bb[8], gwv[8];
#pragma unroll
    for (int ct = 0; ct < 8; ++ct) {
        bb[ct] = bias[ct * 16 + r0];
        if (GATE) gwv[ct] = gw[ct * 16 + r0];
    }
    float gbv = GATE ? gb[0] : 0.f;
    int rbase = tile + (w << 4) + (ch << 2);
#pragma unroll
    for (int reg = 0; reg < 4; ++reg) {
        int row = rbase + reg;
        bool ok = row < n;
        float dvr = (SCALE && ok) ? dis[row] : 1.f;
        float o[8];
        float gp = 0.f;
#pragma unroll
        for (int ct = 0; ct < 8; ++ct) {
            o[ct] = fmaxf(acc[ct][reg] + bb[ct], 0.f);
            if (GATE) gp = fmaf(o[ct], gwv[ct], gp);
        }
        if (ok) {
#pragma unroll
            for (int k = 0; k < 4; ++k) {
                float lo = SCALE ? o[k] * dvr : o[k];
                float hi = SCALE ? o[k + 4] * dvr : o[k + 4];
                out[(size_t)row * 64 + k * 16 + r0] = packbf(lo, hi);
            }
        }
        if (GATE) {
            gp += __shfl_xor(gp, 1);
            gp += __shfl_xor(gp, 2);
            gp += __shfl_xor(gp, 4);
            gp += __shfl_xor(gp, 8);
            if (r0 == 0 && ok) gate[row] = gp + gbv;
        }
    }
}

// --- attention pooling: one wave per graph, inline boundary search ----------
__global__ __launch_bounds__(256) void k_pool(const unsigned int* __restrict__ h,
                                              const float* __restrict__ gate,
                                              const int* __restrict__ batch,
                                              float* __restrict__ emb, int n, int B) {
    int wid = (blockIdx.x * blockDim.x + threadIdx.x) >> 6;
    int lane = threadIdx.x & 63;
    if (wid >= B) return;
    int bnd = 0;
    if (lane < 2) {
        int g = wid + lane;
        int lo = 0, hi = n;
        while (lo < hi) {
            int mid = (lo + hi) >> 1;
            if (batch[mid] < g) lo = mid + 1;
            else hi = mid;
        }
        bnd = lo;
    }
    int s = __shfl(bnd, 0), e2 = __shfl(bnd, 1);
    if (s >= e2) {
        emb[(size_t)wid * 128 + lane] = 0.f;
        emb[(size_t)wid * 128 + 64 + lane] = 0.f;
        return;
    }
    float m = -INFINITY;
    for (int v = s + lane; v < e2; v += 64) m = fmaxf(m, gate[v]);
#pragma unroll
    for (int off = 32; off; off >>= 1) m = fmaxf(m, __shfl_xor(m, off));
    float a0 = 0.f, a1 = 0.f, den = 0.f;
    for (int v = s; v < e2; ++v) {
        float ev = __expf(gate[v] - m);
        den += ev;
        unsigned int hv = h[(size_t)v * 64 + lane];
        a0 = fmaf(ev, b2f(hv << 16), a0);
        a1 = fmaf(ev, b2f(hv & 0xffff0000u), a1);
    }
    float inv = 1.f / den;
    emb[(size_t)wid * 128 + lane] = a0 * inv;       // col lane
    emb[(size_t)wid * 128 + 64 + lane] = a1 * inv;  // col lane+64
}

// --- final projection: 32 graphs per block ----------------------------------
__global__ __launch_bounds__(256) void k_proj(const float* __restrict__ emb,
                                              const float* __restrict__ pw,
                                              const float* __restrict__ pb,
                                              float* __restrict__ out, int B) {
    __shared__ float es[32][128];
    int g0 = blockIdx.x * 32;
    int t = threadIdx.x;
    for (int i = t; i < 1024; i += 256) {
        int g = g0 + (i >> 5);
        float4 val = (g < B) ? ((const float4*)emb)[(size_t)g * 32 + (i & 31)]
                             : make_float4(0.f, 0.f, 0.f, 0.f);
        *(float4*)&es[i >> 5][(i & 31) * 4] = val;
    }
    __syncthreads();
    float acc[32];
#pragma unroll
    for (int i = 0; i < 32; ++i) acc[i] = 0.f;
    for (int k = 0; k < 128; ++k) {
        float wv = pw[k * 256 + t];
#pragma unroll
        for (int i = 0; i < 32; ++i) acc[i] = fmaf(es[i][k], wv, acc[i]);
    }
    float b = pb[t];
#pragma unroll
    for (int i = 0; i < 32; ++i) {
        int g = g0 + i;
        if (g < B) out[(size_t)g * 256 + t] = acc[i] + b;
    }
}

// ---------------------------------------------------------------------------
extern "C" void kernel_launch(void* const* d_in, const int* in_sizes, int n_in,
                              void* d_out, int out_size, void* d_ws, size_t ws_size,
                              hipStream_t stream) {
    const float* x = (const float*)d_in[0];
    const int* ei = (const int*)d_in[1];
    const int* batch = (const int*)d_in[2];
    const float* W0 = (const float*)d_in[3];
    const float* b0 = (const float*)d_in[4];
    const float* W1 = (const float*)d_in[5];
    const float* b1 = (const float*)d_in[6];
    const float* W2 = (const float*)d_in[7];
    const float* b2 = (const float*)d_in[8];
    const float* gw = (const float*)d_in[9];
    const float* gb = (const float*)d_in[10];
    const float* pw = (const float*)d_in[11];
    const float* pb = (const float*)d_in[12];
    float* out = (float*)d_out;

    const int N = in_sizes[2];
    const int E = in_sizes[1] / 2;
    const int B = out_size / 256;
    (void)n_in;

    const int* esrc = ei;
    const int* edst = ei + E;

    char* p = (char*)d_ws;
    auto carve = [&](size_t bytes) {
        char* r = p;
        p += (bytes + 255) & ~(size_t)255;
        return r;
    };
    unsigned int* xd = (unsigned int*)carve((size_t)N * 48 * 4);
    unsigned int* hA = (unsigned int*)carve((size_t)N * 64 * 4);
    unsigned int* hB = (unsigned int*)carve((size_t)N * 64 * 4);
    float* emb = (float*)carve((size_t)B * 128 * 4);
    int* csr_src = (int*)carve((size_t)E * 4);
    int* csr_dst = (int*)carve((size_t)E * 4);
    float* dis = (float*)carve((size_t)N * 4);
    int* cnt = (int*)carve((size_t)2 * N * 4);  // cnt + cur0 (one memset)
    int* cur0 = cnt + N;
    int* rowstart = (int*)carve((size_t)(N + 1) * 4);
    float* gate = (float*)carve((size_t)N * 4);
    int* bsum = (int*)carve((size_t)4096 * 4);
    unsigned short* wp0 = (unsigned short*)carve((size_t)3 * 512 * 8 * 2);
    unsigned short* wp1 = (unsigned short*)carve((size_t)4 * 512 * 8 * 2);
    unsigned short* wp2 = (unsigned short*)carve((size_t)4 * 512 * 8 * 2);
    if ((size_t)(p - (char*)d_ws) > ws_size) return;

    const int nb = (N + 2047) / 2048;

    hipMemsetAsync(cnt, 0, (size_t)2 * N * 4, stream);
    k_count<<<(E + 255) / 256, 256, 0, stream>>>(edst, cnt, E);
    k_scan1<<<nb, 256, 0, stream>>>(cnt, rowstart + 1, bsum, dis, N);
    k_scan2<<<1, 256, 0, stream>>>(bsum, nb);
    k_scan3<<<nb, 256, 0, stream>>>(rowstart, bsum, N);
    k_fill<<<(E + 255) / 256, 256, 0, stream>>>(esrc, edst, rowstart, cur0,
                                                csr_src, csr_dst, E);
    k_cvtw3<<<22, 256, 0, stream>>>(W0, W1, W2, wp0, wp1, wp2);
    k_xd<<<(N * 48 + 255) / 256, 256, 0, stream>>>(x, dis, xd, N);

    const int fb = (N + 63) / 64;

    // layer 0: xd -> hA (pair layout, dis-prescaled)
    k_fused<3, true, false><<<fb, 256, 0, stream>>>(
        xd, dis, rowstart, csr_src, csr_dst, wp0, b0, hA, nullptr, nullptr, nullptr, N);
    // layer 1: hA -> hB
    k_fused<4, true, false><<<fb, 256, 0, stream>>>(
        hA, dis, rowstart, csr_src, csr_dst, wp1, b1, hB, nullptr, nullptr, nullptr, N);
    // layer 2: hB -> hA (unscaled) + gate
    k_fused<4, false, true><<<fb, 256, 0, stream>>>(
        hB, dis, rowstart, csr_src, csr_dst, wp2, b2, hA, gw, gb, gate, N);

    // pooling + projection
    k_pool<<<(B + 3) / 4, 256, 0, stream>>>(hA, gate, batch, emb, N, B);
    k_proj<<<(B + 31) / 32, 256, 0, stream>>>(emb, pw, pb, out, B);
}

// Round 8
// 684.384 us; speedup vs baseline: 3.1986x; 3.1986x over previous
//
#include <hip/hip_runtime.h>
#include <hip/hip_bf16.h>
#include <cstdint>

// ---------------------------------------------------------------------------
// MolGraphEncoder r8: r6 structure (fused layer, register-bucketed gather,
// XOR-swizzled LDS tile, MFMA) with 8-edge-deep gather ILP and a trimmed
// preprocessing chain (dis in scan1, inline pool bounds, single cvtw).
// ---------------------------------------------------------------------------

typedef __attribute__((ext_vector_type(8))) short short8;
typedef __attribute__((ext_vector_type(4))) float f32x4;

__device__ __forceinline__ float b2f(unsigned int hi16) {
    return __builtin_bit_cast(float, hi16);
}
__device__ __forceinline__ unsigned short f2b(float f) {  // RTN-even
    unsigned int u = __builtin_bit_cast(unsigned int, f);
    u += 0x7fffu + ((u >> 16) & 1u);
    return (unsigned short)(u >> 16);
}
__device__ __forceinline__ unsigned int packbf(float lo, float hi) {
    return ((unsigned int)f2b(hi) << 16) | f2b(lo);
}

__global__ void k_count(const int* __restrict__ dst, int* __restrict__ cnt, int E) {
    int e = blockIdx.x * blockDim.x + threadIdx.x;
    if (e < E) atomicAdd(&cnt[dst[e]], 1);
}

// --- scan (2048/block) + fused dis = rsqrt(deg+1) ---------------------------
__global__ void k_scan1(const int* __restrict__ in, int* __restrict__ out1,
                        int* __restrict__ bsum, float* __restrict__ dis, int n) {
    __shared__ int s[256];
    int t = threadIdx.x;
    int base = blockIdx.x * 2048 + t * 8;
    int v[8];
    int run = 0;
#pragma unroll
    for (int i = 0; i < 8; ++i) {
        int idx = base + i;
        int x = (idx < n) ? in[idx] : 0;
        if (idx < n) dis[idx] = rsqrtf((float)x + 1.0f);
        run += x;
        v[i] = run;
    }
    s[t] = run;
    __syncthreads();
    for (int off = 1; off < 256; off <<= 1) {
        int add = (t >= off) ? s[t - off] : 0;
        __syncthreads();
        s[t] += add;
        __syncthreads();
    }
    int pre = (t > 0) ? s[t - 1] : 0;
#pragma unroll
    for (int i = 0; i < 8; ++i) {
        int idx = base + i;
        if (idx < n) out1[idx] = v[i] + pre;
    }
    if (t == 255) bsum[blockIdx.x] = s[255];
}

__global__ void k_scan2(int* bsum, int nb) {
    __shared__ int s[256];
    int t = threadIdx.x;
    s[t] = (t < nb) ? bsum[t] : 0;
    __syncthreads();
    for (int off = 1; off < 256; off <<= 1) {
        int add = (t >= off) ? s[t - off] : 0;
        __syncthreads();
        s[t] += add;
        __syncthreads();
    }
    if (t < nb) bsum[t] = s[t];
}

__global__ void k_scan3(int* __restrict__ rowstart, const int* __restrict__ bsum, int n) {
    int b = blockIdx.x, t = threadIdx.x;
    if (b == 0) {
        if (t == 0) rowstart[0] = 0;
        return;
    }
    int add = bsum[b - 1];
    int* out1 = rowstart + 1;
    int base = b * 2048 + t * 8;
#pragma unroll
    for (int i = 0; i < 8; ++i) {
        int idx = base + i;
        if (idx < n) out1[idx] += add;
    }
}

// fill CSR: position = rowstart[d] + zero-based atomic offset
__global__ void k_fill(const int* __restrict__ src, const int* __restrict__ dst,
                       const int* __restrict__ rowstart, int* __restrict__ cur0,
                       int* __restrict__ csr_src, int E) {
    int e = blockIdx.x * blockDim.x + threadIdx.x;
    if (e >= E) return;
    int d = dst[e];
    int pos = rowstart[d] + atomicAdd(&cur0[d], 1);
    csr_src[pos] = src[e];
}

// --- pack all 3 weights into MFMA B-fragment layout (bf16, K padded) --------
__global__ void k_cvtw3(const float* __restrict__ W0, const float* __restrict__ W1,
                        const float* __restrict__ W2, unsigned short* __restrict__ wp0,
                        unsigned short* __restrict__ wp1, unsigned short* __restrict__ wp2) {
    int tid = blockIdx.x * blockDim.x + threadIdx.x;
    const float* W;
    unsigned short* o;
    int Ksrc, f;
    if (tid < 3 * 512) { W = W0; o = wp0; Ksrc = 82; f = tid; }
    else if (tid < 7 * 512) { W = W1; o = wp1; Ksrc = 128; f = tid - 3 * 512; }
    else if (tid < 11 * 512) { W = W2; o = wp2; Ksrc = 128; f = tid - 7 * 512; }
    else return;
    int lane = f & 63, fr = f >> 6;
    int m = fr >> 3, ct = fr & 7;
    int col = ct * 16 + (lane & 15);
    int kb = m * 32 + ((lane >> 4) << 3);
    unsigned short v[8];
#pragma unroll
    for (int j = 0; j < 8; ++j) {
        int k = kb + j;
        v[j] = (k < Ksrc) ? f2b(W[k * 128 + col]) : (unsigned short)0;
    }
    *(short8*)(o + (size_t)f * 8) = *(short8*)v;
}

// --- xd = bf16(dis[v] * x[v]), 82 cols padded to 96 (48 u32/row) ------------
__global__ __launch_bounds__(256) void k_xd(const float* __restrict__ x,
                                            const float* __restrict__ dis,
                                            unsigned int* __restrict__ xd, int n) {
    int tid = blockIdx.x * blockDim.x + threadIdx.x;
    if (tid >= n * 48) return;
    int v = tid / 48;
    int c = (tid - v * 48) * 2;
    float dv = dis[v];
    const float* xv = x + (size_t)v * 82;
    float fx = (c < 82) ? dv * xv[c] : 0.f;
    float fy = (c + 1 < 82) ? dv * xv[c + 1] : 0.f;
    xd[tid] = packbf(fx, fy);
}

// --- fused GCN layer: gather (8-edge ILP) -> swizzled LDS -> MFMA -----------
// Input rows: RU = KS*16 u32 (2 bf16 each), dis-prescaled by producer.
// agg[v] = dis[v] * ( in[v] + sum_{u->v} in[u] );  out = relu(agg @ W + b)
// SCALE: out *= dis[row] (pre-scale for next layer). GATE: fused gate dot.
template <int KS, bool SCALE, bool GATE>
__global__ __launch_bounds__(256, 6) void k_fused(
    const unsigned int* __restrict__ hd, const float* __restrict__ dis,
    const int* __restrict__ rowstart, const int* __restrict__ csr,
    const unsigned short* __restrict__ Wp, const float* __restrict__ bias,
    unsigned short* __restrict__ out, const float* __restrict__ gw,
    const float* __restrict__ gb, float* __restrict__ gate, int n) {
    constexpr int RU = KS * 16;  // u32 per input row
    __shared__ unsigned int As[64 * 64];  // 64 rows x 256B (zero-padded), swizzled
    int t = threadIdx.x, lane = t & 63, w = t >> 6;
    int tile = blockIdx.x * 64;
    const bool act = (RU == 64) ? true : (lane < RU);
    const int li = act ? lane : 0;

    // ---- phase 1: each wave gathers 16 rows as 4 buckets of 4 (8-edge ILP) --
    for (int g = 0; g < 4; ++g) {
        int r = (w << 4) + g * 4;  // local row of first node in bucket
        int v0 = tile + r;
        unsigned int* dst0 = &As[(r + 0) * 64 + (lane ^ (((r + 0) & 7) << 2))];
        unsigned int* dst1 = &As[(r + 1) * 64 + (lane ^ (((r + 1) & 7) << 2))];
        unsigned int* dst2 = &As[(r + 2) * 64 + (lane ^ (((r + 2) & 7) << 2))];
        unsigned int* dst3 = &As[(r + 3) * 64 + (lane ^ (((r + 3) & 7) << 2))];
        if (v0 >= n) {
            *dst0 = 0u; *dst1 = 0u; *dst2 = 0u; *dst3 = 0u;
            continue;
        }
        int nv = n - v0;
        if (nv > 4) nv = 4;
        int e0 = rowstart[v0];
        int eE = rowstart[v0 + nv];
        int b1 = (nv > 1) ? rowstart[v0 + 1] : eE;
        int b2 = (nv > 2) ? rowstart[v0 + 2] : eE;
        int b3 = (nv > 3) ? rowstart[v0 + 3] : eE;

        unsigned int s0 = hd[(size_t)v0 * RU + li];
        unsigned int s1 = (nv > 1) ? hd[(size_t)(v0 + 1) * RU + li] : 0u;
        unsigned int s2 = (nv > 2) ? hd[(size_t)(v0 + 2) * RU + li] : 0u;
        unsigned int s3 = (nv > 3) ? hd[(size_t)(v0 + 3) * RU + li] : 0u;
        float a0x = b2f(s0 << 16), a0y = b2f(s0 & 0xffff0000u);
        float a1x = b2f(s1 << 16), a1y = b2f(s1 & 0xffff0000u);
        float a2x = b2f(s2 << 16), a2y = b2f(s2 & 0xffff0000u);
        float a3x = b2f(s3 << 16), a3y = b2f(s3 & 0xffff0000u);

        for (int e = e0; e < eE; e += 8) {
            int rem = eE - e;
            // clamped index loads (uniform addresses), 8 rows in flight
            int i1 = (rem > 1) ? e + 1 : e;
            int i2 = (rem > 2) ? e + 2 : e;
            int i3 = (rem > 3) ? e + 3 : e;
            int i4 = (rem > 4) ? e + 4 : e;
            int i5 = (rem > 5) ? e + 5 : e;
            int i6 = (rem > 6) ? e + 6 : e;
            int i7 = (rem > 7) ? e + 7 : e;
            int u0 = csr[e],  u1 = csr[i1], u2 = csr[i2], u3 = csr[i3];
            int u4 = csr[i4], u5 = csr[i5], u6 = csr[i6], u7 = csr[i7];
            unsigned int r0v = hd[(size_t)u0 * RU + li];
            unsigned int r1v = hd[(size_t)u1 * RU + li];
            unsigned int r2v = hd[(size_t)u2 * RU + li];
            unsigned int r3v = hd[(size_t)u3 * RU + li];
            unsigned int r4v = hd[(size_t)u4 * RU + li];
            unsigned int r5v = hd[(size_t)u5 * RU + li];
            unsigned int r6v = hd[(size_t)u6 * RU + li];
            unsigned int r7v = hd[(size_t)u7 * RU + li];
#define ACC(rv, ei)                                                     \
            {                                                           \
                float fx = b2f((rv) << 16), fy = b2f((rv) & 0xffff0000u); \
                if ((ei) < b1) { a0x += fx; a0y += fy; }                \
                else if ((ei) < b2) { a1x += fx; a1y += fy; }           \
                else if ((ei) < b3) { a2x += fx; a2y += fy; }           \
                else { a3x += fx; a3y += fy; }                          \
            }
            ACC(r0v, e)
            if (rem > 1) ACC(r1v, e + 1)
            if (rem > 2) ACC(r2v, e + 2)
            if (rem > 3) ACC(r3v, e + 3)
            if (rem > 4) ACC(r4v, e + 4)
            if (rem > 5) ACC(r5v, e + 5)
            if (rem > 6) ACC(r6v, e + 6)
            if (rem > 7) ACC(r7v, e + 7)
#undef ACC
        }

        float d0 = dis[v0];
        float d1 = (nv > 1) ? dis[v0 + 1] : 0.f;
        float d2 = (nv > 2) ? dis[v0 + 2] : 0.f;
        float d3 = (nv > 3) ? dis[v0 + 3] : 0.f;
        *dst0 = act ? packbf(d0 * a0x, d0 * a0y) : 0u;
        *dst1 = (act && nv > 1) ? packbf(d1 * a1x, d1 * a1y) : 0u;
        *dst2 = (act && nv > 2) ? packbf(d2 * a2x, d2 * a2y) : 0u;
        *dst3 = (act && nv > 3) ? packbf(d3 * a3x, d3 * a3y) : 0u;
    }
    __syncthreads();

    // ---- phase 2: 16-row MFMA strip per wave ----
    int r0 = lane & 15, ch = lane >> 4;
    const unsigned int* arow = &As[((w << 4) + r0) << 6];
    f32x4 acc[8];
#pragma unroll
    for (int ct = 0; ct < 8; ++ct) acc[ct] = (f32x4){0.f, 0.f, 0.f, 0.f};
#pragma unroll
    for (int m = 0; m < KS; ++m) {
        int slot = (ch + 4 * m) ^ (r0 & 7);
        short8 a = *(const short8*)(arow + slot * 4);
        const short8* wf = (const short8*)Wp + ((size_t)(m * 8) * 64 + lane);
#pragma unroll
        for (int ct = 0; ct < 8; ++ct) {
            short8 b = wf[ct * 64];
            acc[ct] = __builtin_amdgcn_mfma_f32_16x16x32_bf16(a, b, acc[ct], 0, 0, 0);
        }
    }

    // ---- epilogue ----
    int cq = r0;
    float bb[8], gwv[8];
#pragma unroll
    for (int ct = 0; ct < 8; ++ct) {
        bb[ct] = bias[ct * 16 + cq];
        if (GATE) gwv[ct] = gw[ct * 16 + cq];
    }
    float gbv = GATE ? gb[0] : 0.f;
    int rbase = tile + (w << 4) + (ch << 2);
#pragma unroll
    for (int reg = 0; reg < 4; ++reg) {
        int row = rbase + reg;
        bool ok = row < n;
        float dv = (SCALE && ok) ? dis[row] : 1.f;
        float gp = 0.f;
#pragma unroll
        for (int ct = 0; ct < 8; ++ct) {
            float o = fmaxf(acc[ct][reg] + bb[ct], 0.f);
            if (GATE) gp = fmaf(o, gwv[ct], gp);
            if (ok) out[(size_t)row * 128 + ct * 16 + cq] = f2b(SCALE ? o * dv : o);
        }
        if (GATE) {
            gp += __shfl_xor(gp, 1);
            gp += __shfl_xor(gp, 2);
            gp += __shfl_xor(gp, 4);
            gp += __shfl_xor(gp, 8);
            if (cq == 0 && ok) gate[row] = gp + gbv;
        }
    }
}

// --- attention pooling: one wave per graph, inline boundary search ----------
__global__ __launch_bounds__(256) void k_pool(const unsigned short* __restrict__ h,
                                              const float* __restrict__ gate,
                                              const int* __restrict__ batch,
                                              float* __restrict__ emb, int n, int B) {
    int wid = (blockIdx.x * blockDim.x + threadIdx.x) >> 6;
    int lane = threadIdx.x & 63;
    if (wid >= B) return;
    int bnd = 0;
    if (lane < 2) {
        int g = wid + lane;
        int lo = 0, hi = n;
        while (lo < hi) {
            int mid = (lo + hi) >> 1;
            if (batch[mid] < g) lo = mid + 1;
            else hi = mid;
        }
        bnd = lo;
    }
    int s = __shfl(bnd, 0), e2 = __shfl(bnd, 1);
    float* ev2 = emb + (size_t)wid * 128 + lane * 2;
    if (s >= e2) {
        ev2[0] = 0.f;
        ev2[1] = 0.f;
        return;
    }
    float m = -INFINITY;
    for (int v = s + lane; v < e2; v += 64) m = fmaxf(m, gate[v]);
#pragma unroll
    for (int off = 32; off; off >>= 1) m = fmaxf(m, __shfl_xor(m, off));
    float a0 = 0.f, a1 = 0.f, den = 0.f;
    for (int v = s; v < e2; ++v) {
        float ev = __expf(gate[v] - m);
        den += ev;
        unsigned int hv = *(const unsigned int*)((const char*)h + (size_t)v * 256 + lane * 4);
        a0 = fmaf(ev, b2f(hv << 16), a0);
        a1 = fmaf(ev, b2f(hv & 0xffff0000u), a1);
    }
    float inv = 1.f / den;
    ev2[0] = a0 * inv;
    ev2[1] = a1 * inv;
}

// --- final projection: 32 graphs per block ----------------------------------
__global__ __launch_bounds__(256) void k_proj(const float* __restrict__ emb,
                                              const float* __restrict__ pw,
                                              const float* __restrict__ pb,
                                              float* __restrict__ out, int B) {
    __shared__ float es[32][128];
    int g0 = blockIdx.x * 32;
    int t = threadIdx.x;
    for (int i = t; i < 1024; i += 256) {
        int g = g0 + (i >> 5);
        float4 val = (g < B) ? ((const float4*)emb)[(size_t)g * 32 + (i & 31)]
                             : make_float4(0.f, 0.f, 0.f, 0.f);
        *(float4*)&es[i >> 5][(i & 31) * 4] = val;
    }
    __syncthreads();
    float acc[32];
#pragma unroll
    for (int i = 0; i < 32; ++i) acc[i] = 0.f;
    for (int k = 0; k < 128; ++k) {
        float wv = pw[k * 256 + t];
#pragma unroll
        for (int i = 0; i < 32; ++i) acc[i] = fmaf(es[i][k], wv, acc[i]);
    }
    float b = pb[t];
#pragma unroll
    for (int i = 0; i < 32; ++i) {
        int g = g0 + i;
        if (g < B) out[(size_t)g * 256 + t] = acc[i] + b;
    }
}

// ---------------------------------------------------------------------------
extern "C" void kernel_launch(void* const* d_in, const int* in_sizes, int n_in,
                              void* d_out, int out_size, void* d_ws, size_t ws_size,
                              hipStream_t stream) {
    const float* x = (const float*)d_in[0];
    const int* ei = (const int*)d_in[1];
    const int* batch = (const int*)d_in[2];
    const float* W0 = (const float*)d_in[3];
    const float* b0 = (const float*)d_in[4];
    const float* W1 = (const float*)d_in[5];
    const float* b1 = (const float*)d_in[6];
    const float* W2 = (const float*)d_in[7];
    const float* b2 = (const float*)d_in[8];
    const float* gw = (const float*)d_in[9];
    const float* gb = (const float*)d_in[10];
    const float* pw = (const float*)d_in[11];
    const float* pb = (const float*)d_in[12];
    float* out = (float*)d_out;

    const int N = in_sizes[2];
    const int E = in_sizes[1] / 2;
    const int B = out_size / 256;
    (void)n_in;

    const int* esrc = ei;
    const int* edst = ei + E;

    char* p = (char*)d_ws;
    auto carve = [&](size_t bytes) {
        char* r = p;
        p += (bytes + 255) & ~(size_t)255;
        return r;
    };
    unsigned int* xd = (unsigned int*)carve((size_t)N * 48 * 4);
    unsigned int* hA = (unsigned int*)carve((size_t)N * 64 * 4);
    unsigned int* hB = (unsigned int*)carve((size_t)N * 64 * 4);
    float* emb = (float*)carve((size_t)B * 128 * 4);
    int* csr_src = (int*)carve((size_t)E * 4);
    float* dis = (float*)carve((size_t)N * 4);
    int* cnt = (int*)carve((size_t)2 * N * 4);  // cnt + cur0 (one memset)
    int* cur0 = cnt + N;
    int* rowstart = (int*)carve((size_t)(N + 1) * 4);
    float* gate = (float*)carve((size_t)N * 4);
    int* bsum = (int*)carve((size_t)4096 * 4);
    unsigned short* wp0 = (unsigned short*)carve((size_t)3 * 512 * 8 * 2);
    unsigned short* wp1 = (unsigned short*)carve((size_t)4 * 512 * 8 * 2);
    unsigned short* wp2 = (unsigned short*)carve((size_t)4 * 512 * 8 * 2);
    if ((size_t)(p - (char*)d_ws) > ws_size) return;

    const int nb = (N + 2047) / 2048;

    hipMemsetAsync(cnt, 0, (size_t)2 * N * 4, stream);
    k_count<<<(E + 255) / 256, 256, 0, stream>>>(edst, cnt, E);
    k_scan1<<<nb, 256, 0, stream>>>(cnt, rowstart + 1, bsum, dis, N);
    k_scan2<<<1, 256, 0, stream>>>(bsum, nb);
    k_scan3<<<nb, 256, 0, stream>>>(rowstart, bsum, N);
    k_fill<<<(E + 255) / 256, 256, 0, stream>>>(esrc, edst, rowstart, cur0, csr_src, E);
    k_cvtw3<<<22, 256, 0, stream>>>(W0, W1, W2, wp0, wp1, wp2);
    k_xd<<<(N * 48 + 255) / 256, 256, 0, stream>>>(x, dis, xd, N);

    const int fb = (N + 63) / 64;

    // layer 0: xd -> hA (bf16, dis-prescaled)
    k_fused<3, true, false><<<fb, 256, 0, stream>>>(
        xd, dis, rowstart, csr_src, wp0, b0, (unsigned short*)hA,
        nullptr, nullptr, nullptr, N);
    // layer 1: hA -> hB (bf16, dis-prescaled)
    k_fused<4, true, false><<<fb, 256, 0, stream>>>(
        hA, dis, rowstart, csr_src, wp1, b1, (unsigned short*)hB,
        nullptr, nullptr, nullptr, N);
    // layer 2: hB -> hA (unscaled) + gate
    k_fused<4, false, true><<<fb, 256, 0, stream>>>(
        hB, dis, rowstart, csr_src, wp2, b2, (unsigned short*)hA,
        gw, gb, gate, N);

    // pooling + projection
    k_pool<<<(B + 3) / 4, 256, 0, stream>>>((const unsigned short*)hA, gate, batch,
                                            emb, N, B);
    k_proj<<<(B + 31) / 32, 256, 0, stream>>>(emb, pw, pb, out, B);
}